// Round 2
// baseline (16435.210 us; speedup 1.0000x reference)
//
#include <hip/hip_runtime.h>
#include <cstddef>

typedef unsigned int uint;
typedef unsigned short ushort;

// ---- problem constants (from reference) ----
constexpr int BATCH = 2;
constexpr int SEQ   = 2523;
constexpr int CDIM  = 768;
constexpr int NH    = 12;
constexpr int HD    = 64;
constexpr int NM    = 1682;               // template rows
constexpr int NMEM  = 4096;
constexpr int NFULL = NMEM + SEQ;         // 6619
constexpr int TOPM  = 841;                // int(0.50*1682)
constexpr int TOPS  = 1654;               // int(0.25*6619)
constexpr int IDC   = CDIM + NH;          // 780

using bf16x8 = __attribute__((ext_vector_type(8))) short;   // 8 bf16 = 4 VGPRs
using f32x4  = __attribute__((ext_vector_type(4))) float;

__device__ __forceinline__ float bf2f(ushort u){ return __uint_as_float(((uint)u) << 16); }
__device__ __forceinline__ ushort f2bf(float f){
  uint x = __float_as_uint(f);
  x += 0x7fffu + ((x >> 16) & 1u);        // RNE
  return (ushort)(x >> 16);
}
// monotone key: larger float -> larger uint
__device__ __forceinline__ uint fkey(float f){
  uint u = __float_as_uint(f);
  return u ^ (uint)(((int)u >> 31) | 0x80000000);
}

// ======================= dtype detector =======================
// bf16 data: bits[14:7] of each 32b word = exponent of a Gaussian bf16 (narrow band).
// fp32 data: bits[14:7] = mantissa bits (uniform). Vote over 256 samples of w_qkv.
__global__ void detect_mode(const uint* __restrict__ w, int* __restrict__ mode){
  __shared__ int cnt;
  if (threadIdx.x == 0) cnt = 0;
  __syncthreads();
  uint v = w[threadIdx.x * 97];           // max idx 24735 words — in-bounds for both dtypes
  uint e = (v >> 7) & 0xFFu;
  if (e >= 100u && e <= 135u) atomicAdd(&cnt, 1);
  __syncthreads();
  if (threadIdx.x == 0) mode[0] = (cnt > 128) ? 1 : 0;   // 1 = bf16, 0 = fp32
}

// ======================= input conversion =======================
__global__ void conv_in(const void* __restrict__ src, ushort* __restrict__ dst,
                        int n, const int* __restrict__ modep){
  int i = blockIdx.x*256 + threadIdx.x;
  if (i >= n) return;
  if (modep[0]) dst[i] = ((const ushort*)src)[i];
  else          dst[i] = f2bf(((const float*)src)[i]);
}

__global__ void conv_bias(const void* __restrict__ src, float* __restrict__ dst,
                          int n, const int* __restrict__ modep){
  int i = blockIdx.x*256 + threadIdx.x;
  if (i >= n) return;
  dst[i] = modep[0] ? bf2f(((const ushort*)src)[i]) : ((const float*)src)[i];
}

// mem_k/mem_v -> head of kfull/vfull (bf16, row j of slice bh at (bh*NFULL+j)*64)
__global__ void conv_mem(const void* __restrict__ mk, const void* __restrict__ mv,
                         ushort* __restrict__ kf, ushort* __restrict__ vf,
                         const int* __restrict__ modep){
  int idx = blockIdx.x*256 + threadIdx.x;
  constexpr int total = BATCH*NH*NMEM*HD;
  if (idx >= total) return;
  int dd = idx & 63;
  int j  = (idx >> 6) % NMEM;
  int bh = idx / (NMEM*HD);
  size_t o = ((size_t)bh*NFULL + j)*HD + dd;
  ushort k_, v_;
  if (modep[0]){ k_ = ((const ushort*)mk)[idx]; v_ = ((const ushort*)mv)[idx]; }
  else { k_ = f2bf(((const float*)mk)[idx]); v_ = f2bf(((const float*)mv)[idx]); }
  kf[o] = k_;
  vf[o] = v_;
}

// ======================= GEMM core macro-ish helpers =======================
// A: (M,K) bf16 row-major, B: (N,K) bf16 row-major (X @ W^T). fp32 MFMA accumulate.
// Staging + MFMA identical to the verified m97 structure (128x128 tile, 16x16x32).

#define GEMM_PROLOGUE(M_, Nc_, K_) \
  __shared__ ushort As[128][40]; \
  __shared__ ushort Bs[128][40]; \
  const int tid  = threadIdx.x; \
  const int wave = tid >> 6, lane = tid & 63; \
  const int quad = lane >> 4, l16 = lane & 15; \
  const int row0 = blockIdx.x * 128, col0 = blockIdx.y * 128; \
  const int wr = (wave >> 1) * 64, wc = (wave & 1) * 64; \
  f32x4 acc[4][4] = {}; \
  for (int k0 = 0; k0 < (K_); k0 += 32){ \
    __syncthreads(); \
    for (int c = tid; c < 512; c += 256){ \
      int r = c >> 2, ck = c & 3; \
      uint4 v = {0,0,0,0}; \
      int gr = row0 + r; \
      if (gr < (M_)) v = *(const uint4*)(A + (size_t)gr * (K_) + k0 + ck*8); \
      *(uint4*)(&As[r][ck*8]) = v; \
    } \
    for (int c = tid; c < 512; c += 256){ \
      int r = c >> 2, ck = c & 3; \
      uint4 v = {0,0,0,0}; \
      int gc = col0 + r; \
      if (gc < (Nc_)) v = *(const uint4*)(Bw + (size_t)gc * (K_) + k0 + ck*8); \
      *(uint4*)(&Bs[r][ck*8]) = v; \
    } \
    __syncthreads(); \
    bf16x8 af[4], bfr[4]; \
    _Pragma("unroll") \
    for (int i = 0; i < 4; i++) af[i]  = *(const bf16x8*)(&As[wr + 16*i + l16][quad*8]); \
    _Pragma("unroll") \
    for (int j = 0; j < 4; j++) bfr[j] = *(const bf16x8*)(&Bs[wc + 16*j + l16][quad*8]); \
    _Pragma("unroll") \
    for (int i = 0; i < 4; i++) \
      _Pragma("unroll") \
      for (int j = 0; j < 4; j++) \
        acc[i][j] = __builtin_amdgcn_mfma_f32_16x16x32_bf16(af[i], bfr[j], acc[i][j], 0, 0, 0); \
  }
// C/D layout (verified m89/m91): col = lane&15, row = (lane>>4)*4 + reg

// --- id_kv GEMM: fp32 out + fp32 bias ---
__global__ __launch_bounds__(256)
void gemm_idkv(const ushort* __restrict__ A, const ushort* __restrict__ Bw,
               const float* __restrict__ biasf, float* __restrict__ Cf)
{
  constexpr int M = BATCH*NM, Nc = IDC, K = CDIM;
  GEMM_PROLOGUE(M, Nc, K)
  #pragma unroll
  for (int i = 0; i < 4; i++)
    #pragma unroll
    for (int j = 0; j < 4; j++)
      #pragma unroll
      for (int r = 0; r < 4; r++){
        int row = row0 + wr + 16*i + quad*4 + r;
        int col = col0 + wc + 16*j + l16;
        if (row < M && col < Nc)
          Cf[(size_t)row*Nc + col] = acc[i][j][r] + biasf[col];
      }
}

// --- qkv GEMM with fused epilogue ---
// q -> qall (fp32, scaled); k -> kfull tail + kmod(bf16) + out_km; v -> vfull tail + out_vm.
__global__ __launch_bounds__(256)
void gemm_qkv(const ushort* __restrict__ A, const ushort* __restrict__ Bw,
              const float* __restrict__ idkvf, float* __restrict__ qall,
              ushort* __restrict__ kfull, ushort* __restrict__ vfull,
              ushort* __restrict__ kmod, void* __restrict__ out_base,
              const int* __restrict__ modep)
{
  constexpr int M = BATCH*SEQ, Nc = 3*CDIM, K = CDIM;
  GEMM_PROLOGUE(M, Nc, K)
  const int mode = modep[0];
  constexpr size_t OKM = (size_t)BATCH*SEQ*CDIM;            // out_km elem offset
  constexpr size_t OVM = OKM + (size_t)BATCH*NH*NM*HD;      // out_vm elem offset
  #pragma unroll
  for (int i = 0; i < 4; i++)
    #pragma unroll
    for (int j = 0; j < 4; j++)
      #pragma unroll
      for (int r = 0; r < 4; r++){
        int row = row0 + wr + 16*i + quad*4 + r;
        int col = col0 + wc + 16*j + l16;
        if (row < M && col < Nc){
          float v = acc[i][j][r];
          int b = row / SEQ, n = row - b*SEQ;
          if (col < CDIM){
            int h = col >> 6, dd = col & 63;
            qall[((size_t)(b*NH+h)*SEQ + n)*HD + dd] = v * 0.125f;
          } else if (col < 2*CDIM){
            int c = col - CDIM; int h = c >> 6, dd = c & 63;
            size_t bh = (size_t)b*NH + h;
            kfull[(bh*NFULL + NMEM + n)*HD + dd] = f2bf(v);   // unmodified k
            if (n < NM){
              float idk = idkvf[((size_t)b*NM + n)*IDC + h];
              float km = v * (1.f + tanhf(idk));
              size_t o = (bh*NM + n)*HD + dd;
              kmod[o] = f2bf(km);
              if (mode) ((ushort*)out_base)[OKM + o] = f2bf(km);
              else      ((float*) out_base)[OKM + o] = km;
            }
          } else {
            int c = col - 2*CDIM; int h = c >> 6, dd = c & 63;
            size_t bh = (size_t)b*NH + h;
            float vv = v;
            if (n < NM){
              vv = v + idkvf[((size_t)b*NM + n)*IDC + NH + c];
              size_t o = (bh*NM + n)*HD + dd;
              if (mode) ((ushort*)out_base)[OVM + o] = f2bf(vv);
              else      ((float*) out_base)[OVM + o] = vv;
            }
            vfull[(bh*NFULL + NMEM + n)*HD + dd] = f2bf(vv);
          }
        }
      }
}

// --- proj GEMM: bias + mode-dtype output ---
__global__ __launch_bounds__(256)
void gemm_proj(const ushort* __restrict__ A, const ushort* __restrict__ Bw,
               const float* __restrict__ biasf, void* __restrict__ out_base,
               const int* __restrict__ modep)
{
  constexpr int M = BATCH*SEQ, Nc = CDIM, K = CDIM;
  GEMM_PROLOGUE(M, Nc, K)
  const int mode = modep[0];
  #pragma unroll
  for (int i = 0; i < 4; i++)
    #pragma unroll
    for (int j = 0; j < 4; j++)
      #pragma unroll
      for (int r = 0; r < 4; r++){
        int row = row0 + wr + 16*i + quad*4 + r;
        int col = col0 + wc + 16*j + l16;
        if (row < M && col < Nc){
          float v = acc[i][j][r] + biasf[col];
          size_t o = (size_t)row*Nc + col;
          if (mode) ((ushort*)out_base)[o] = f2bf(v);
          else      ((float*) out_base)[o] = v;
        }
      }
}

// ======================= fused top-k attention =======================
// One WG per RQ q-rows of one (b,h). Score row(s) in LDS; exact 4-pass radix top-k
// on monotone uint keys; sparse AV skipping unselected rows (wave-uniform branch).
template<int RQ>
__global__ __launch_bounds__(256)
void attn_topk(const float* __restrict__ qall, const ushort* __restrict__ Kp,
               const ushort* __restrict__ Vp, ushort* __restrict__ xout,
               int qbase, int Kn, int ksel, int ldK, int ldV)
{
  extern __shared__ char smem[];
  float* sc = (float*)smem;                                    // RQ*Kn fp32 scores
  size_t off = ((size_t)RQ*Kn*4 + 15) & ~(size_t)15;
  ushort* kt = (ushort*)(smem + off);  off += 256*68*2;        // K tile, row stride 68 bf16
  float* qr  = (float*)(smem + off);   off += (size_t)RQ*64*4; // q rows
  float* red = (float*)(smem + off);   off += 256*4;           // reductions
  uint* hist = (uint*)(smem + off);    off += 256*4;           // radix histogram
  uint* ctrlu = (uint*)(smem + off);                           // [0]=prefix [1]=need [2]=eq_ctr
  float* ctrlf = (float*)(ctrlu + 4);                          // [0]=Z

  const int tid = threadIdx.x;
  const int bh  = blockIdx.y;
  const int b = bh / NH, h = bh % NH;
  const int g0 = blockIdx.x * RQ;
  const ushort* Kb = Kp + (size_t)bh * ldK;
  const ushort* Vb = Vp + (size_t)bh * ldV;

  for (int t = tid; t < RQ*64; t += 256){
    int r = t >> 6, dd = t & 63;
    int qi = qbase + g0 + r;
    qr[t] = qall[((size_t)bh*SEQ + qi)*HD + dd];
  }

  float pmax[RQ];
  #pragma unroll
  for (int r = 0; r < RQ; r++) pmax[r] = -3e38f;

  // ---- score phase: stage 256 K-rows to LDS, each thread dots one row vs RQ q's ----
  for (int t0 = 0; t0 < Kn; t0 += 256){
    __syncthreads();
    int nrow = Kn - t0; if (nrow > 256) nrow = 256;
    for (int idx = tid; idx < nrow*16; idx += 256){
      int r = idx >> 4, cc = idx & 15;
      *(uint2*)(kt + r*68 + cc*4) = *(const uint2*)(Kb + (size_t)(t0 + r)*HD + cc*4);
    }
    __syncthreads();
    int j = t0 + tid;
    if (j < Kn){
      const ushort* krow = kt + tid*68;
      #pragma unroll
      for (int r = 0; r < RQ; r++){
        const float* q = qr + r*64;
        float s = 0.f;
        #pragma unroll
        for (int c = 0; c < 64; c += 4){
          uint2 u = *(const uint2*)(krow + c);
          s += q[c]   * __uint_as_float(u.x << 16);
          s += q[c+1] * __uint_as_float(u.x & 0xffff0000u);
          s += q[c+2] * __uint_as_float(u.y << 16);
          s += q[c+3] * __uint_as_float(u.y & 0xffff0000u);
        }
        sc[(size_t)r*Kn + j] = s;
        pmax[r] = fmaxf(pmax[r], s);
      }
    }
  }

  // ---- per q-row: max, radix top-k select, softmax-mark, sparse AV ----
  for (int r = 0; r < RQ; r++){
    __syncthreads();
    red[tid] = pmax[r];
    __syncthreads();
    for (int s1 = 128; s1 > 0; s1 >>= 1){
      if (tid < s1) red[tid] = fmaxf(red[tid], red[tid+s1]);
      __syncthreads();
    }
    float m = red[0];
    float* scr = sc + (size_t)r*Kn;

    uint prefix = 0, need = (uint)ksel;
    for (int pass = 0; pass < 4; pass++){
      int shift = 24 - 8*pass;
      hist[tid] = 0;
      __syncthreads();
      for (int j = tid; j < Kn; j += 256){
        uint key = fkey(scr[j]);
        bool match = (pass == 0) || ((key >> (shift+8)) == (prefix >> (shift+8)));
        if (match) atomicAdd(&hist[(key >> shift) & 255], 1u);
      }
      __syncthreads();
      if (tid == 0){
        uint cum = 0; int bsel = 0;
        for (int bb = 255; bb >= 0; bb--){
          uint hc = hist[bb];
          if (cum + hc >= need){ bsel = bb; break; }
          cum += hc;
        }
        ctrlu[0] = prefix | ((uint)bsel << shift);
        ctrlu[1] = need - cum;
      }
      __syncthreads();
      prefix = ctrlu[0]; need = ctrlu[1];
      __syncthreads();
    }
    const uint tkey = prefix, need_eq = need;  // kth-largest key; #ties to take

    if (tid == 0){ ctrlu[2] = 0; ctrlf[0] = 0.f; }
    __syncthreads();
    float zl = 0.f;
    for (int j = tid; j < Kn; j += 256){
      float s = scr[j];
      uint key = fkey(s);
      float e = 0.f;
      if (key > tkey) e = __expf(s - m) == 0.f ? expf(s - m) : expf(s - m);
      else if (key == tkey){
        uint rk = atomicAdd(&ctrlu[2], 1u);
        if (rk < need_eq) e = expf(s - m);
      }
      scr[j] = e;
      zl += e;
    }
    atomicAdd(ctrlf, zl);
    __syncthreads();
    float zinv = 1.f / ctrlf[0];

    int g = tid >> 6, lane = tid & 63;
    float acc = 0.f;
    for (int j = g; j < Kn; j += 4){
      float e = scr[j];                       // wave-uniform per j
      if (e > 0.f) acc += e * bf2f(Vb[(size_t)j*HD + lane]);
    }
    red[tid] = acc;
    __syncthreads();
    if (tid < 64){
      float o = (red[tid] + red[tid+64] + red[tid+128] + red[tid+192]) * zinv;
      int qi = qbase + g0 + r;
      xout[((size_t)b*SEQ + qi)*CDIM + h*HD + tid] = f2bf(o);
    }
    __syncthreads();
  }
}

// ======================= launch =======================
extern "C" void kernel_launch(void* const* d_in, const int* in_sizes, int n_in,
                              void* d_out, int out_size, void* d_ws, size_t ws_size,
                              hipStream_t stream)
{
  const void* x        = d_in[0];
  const void* id_total = d_in[1];
  const void* mem_k    = d_in[2];
  const void* mem_v    = d_in[3];
  const void* w_qkv    = d_in[4];
  const void* w_proj   = d_in[5];
  const void* b_proj   = d_in[6];
  const void* w_idkv   = d_in[7];
  const void* b_idkv   = d_in[8];

  char* p = (char*)d_ws;
  auto carve = [&](size_t bytes)->char*{
    char* q = p; p += (bytes + 255) & ~(size_t)255; return q;
  };
  int*    modep  = (int*)   carve(256);
  ushort* xb     = (ushort*)carve(2ull*BATCH*SEQ*CDIM);
  ushort* idb    = (ushort*)carve(2ull*BATCH*NM*CDIM);
  ushort* wqkvb  = (ushort*)carve(2ull*3*CDIM*CDIM);
  ushort* wprojb = (ushort*)carve(2ull*CDIM*CDIM);
  ushort* widkvb = (ushort*)carve(2ull*IDC*CDIM);
  float*  bprojf = (float*) carve(4ull*CDIM);
  float*  bidkvf = (float*) carve(4ull*IDC);
  float*  idkvf  = (float*) carve(4ull*BATCH*NM*IDC);
  float*  qall   = (float*) carve(4ull*BATCH*NH*SEQ*HD);
  ushort* kfull  = (ushort*)carve(2ull*BATCH*NH*NFULL*HD);
  ushort* vfull  = (ushort*)carve(2ull*BATCH*NH*NFULL*HD);
  ushort* kmod   = (ushort*)carve(2ull*BATCH*NH*NM*HD);
  ushort* xcat   = (ushort*)carve(2ull*BATCH*SEQ*CDIM);

  dim3 blk(256,1,1);

  // 0. detect input dtype (bf16 vs fp32) from w_qkv bit patterns
  hipLaunchKernelGGL(detect_mode, dim3(1), blk, 0, stream, (const uint*)w_qkv, modep);

  // 1. canonicalize inputs to bf16 (weights/activations) and fp32 (biases)
  auto conv = [&](const void* src, ushort* dst, int n){
    hipLaunchKernelGGL(conv_in, dim3((n+255)/256), blk, 0, stream, src, dst, n, modep);
  };
  conv(x,        xb,     BATCH*SEQ*CDIM);
  conv(id_total, idb,    BATCH*NM*CDIM);
  conv(w_qkv,    wqkvb,  3*CDIM*CDIM);
  conv(w_proj,   wprojb, CDIM*CDIM);
  conv(w_idkv,   widkvb, IDC*CDIM);
  hipLaunchKernelGGL(conv_bias, dim3((CDIM+255)/256), blk, 0, stream, b_proj, bprojf, CDIM, modep);
  hipLaunchKernelGGL(conv_bias, dim3((IDC+255)/256),  blk, 0, stream, b_idkv, bidkvf, IDC, modep);
  { // mem_k/mem_v -> kfull/vfull head
    constexpr int total = BATCH*NH*NMEM*HD;
    hipLaunchKernelGGL(conv_mem, dim3((total+255)/256), blk, 0, stream,
                       mem_k, mem_v, kfull, vfull, modep);
  }

  // 2. id_kv = id_total @ w_idkv^T + b_idkv (fp32)
  {
    int M = BATCH*NM, Nc = IDC;
    dim3 grid((M+127)/128, (Nc+127)/128, 1);
    hipLaunchKernelGGL(gemm_idkv, grid, blk, 0, stream, idb, widkvb, bidkvf, idkvf);
  }

  // 3. qkv GEMM + fused epilogue (qall, kfull tail, kmod, vfull tail, out_km, out_vm)
  {
    int M = BATCH*SEQ, Nc = 3*CDIM;
    dim3 grid((M+127)/128, (Nc+127)/128, 1);
    hipLaunchKernelGGL(gemm_qkv, grid, blk, 0, stream,
                       xb, wqkvb, idkvf, qall, kfull, vfull, kmod, d_out, modep);
  }

  // 4. template attention: q rows [0,NM), K=kmod, V=v_m_mod (inside vfull), top 841/1682
  {
    size_t lds = (((size_t)2*NM*4 + 15) & ~(size_t)15) + 256*68*2 + 2*64*4 + 256*4 + 256*4 + 32;
    dim3 grid(NM/2, BATCH*NH, 1);
    hipLaunchKernelGGL((attn_topk<2>), grid, blk, lds, stream,
                       qall, kmod, vfull + (size_t)NMEM*HD, xcat,
                       0, NM, TOPM, NM*HD, NFULL*HD);
  }
  // 5. search attention: q rows [NM,SEQ), K=kfull, V=vfull, top 1654/6619
  {
    size_t lds = (((size_t)NFULL*4 + 15) & ~(size_t)15) + 256*68*2 + 64*4 + 256*4 + 256*4 + 32;
    dim3 grid(SEQ - NM, BATCH*NH, 1);
    hipLaunchKernelGGL((attn_topk<1>), grid, blk, lds, stream,
                       qall, kfull, vfull, xcat,
                       NM, NFULL, TOPS, NFULL*HD, NFULL*HD);
  }

  // 6. out = x_concat @ w_proj^T + b_proj
  {
    int M = BATCH*SEQ, Nc = CDIM;
    dim3 grid((M+127)/128, (Nc+127)/128, 1);
    hipLaunchKernelGGL(gemm_proj, grid, blk, 0, stream, xcat, wprojb, bprojf, d_out, modep);
  }
}

// Round 3
// 2694.623 us; speedup vs baseline: 6.0993x; 6.0993x over previous
//
#include <hip/hip_runtime.h>
#include <cstddef>

typedef unsigned int uint;
typedef unsigned short ushort;

// ---- problem constants (from reference) ----
constexpr int BATCH = 2;
constexpr int SEQ   = 2523;
constexpr int CDIM  = 768;
constexpr int NH    = 12;
constexpr int HD    = 64;
constexpr int NM    = 1682;               // template rows
constexpr int NMEM  = 4096;
constexpr int NFULL = NMEM + SEQ;         // 6619
constexpr int NFT   = 6624;               // vT padded row stride (mult of 8)
constexpr int TOPM  = 841;                // int(0.50*1682)
constexpr int TOPS  = 1654;               // int(0.25*6619)
constexpr int IDC   = CDIM + NH;          // 780
constexpr int KNP_S = 6624;               // search slab row stride (mult of 8)
constexpr int KNP_T = 1688;               // template slab row stride

using bf16x8 = __attribute__((ext_vector_type(8))) short;
using f32x4  = __attribute__((ext_vector_type(4))) float;

__device__ __forceinline__ float bf2f(ushort u){ return __uint_as_float(((uint)u) << 16); }
__device__ __forceinline__ ushort f2bf(float f){
  uint x = __float_as_uint(f);
  x += 0x7fffu + ((x >> 16) & 1u);        // RNE
  return (ushort)(x >> 16);
}

// ======================= dtype detector =======================
__global__ void detect_mode(const uint* __restrict__ w, int* __restrict__ mode){
  __shared__ int cnt;
  if (threadIdx.x == 0) cnt = 0;
  __syncthreads();
  uint v = w[threadIdx.x * 97];
  uint e = (v >> 7) & 0xFFu;
  if (e >= 100u && e <= 135u) atomicAdd(&cnt, 1);
  __syncthreads();
  if (threadIdx.x == 0) mode[0] = (cnt > 128) ? 1 : 0;   // 1 = bf16, 0 = fp32
}

// ======================= input conversion =======================
__global__ void conv_in(const void* __restrict__ src, ushort* __restrict__ dst,
                        int n, const int* __restrict__ modep){
  int i = blockIdx.x*256 + threadIdx.x;
  if (i >= n) return;
  if (modep[0]) dst[i] = ((const ushort*)src)[i];
  else          dst[i] = f2bf(((const float*)src)[i]);
}

__global__ void conv_bias(const void* __restrict__ src, float* __restrict__ dst,
                          int n, const int* __restrict__ modep){
  int i = blockIdx.x*256 + threadIdx.x;
  if (i >= n) return;
  dst[i] = modep[0] ? bf2f(((const ushort*)src)[i]) : ((const float*)src)[i];
}

// mem_k -> kfull head (row-major K rows); mem_v -> vT head (transposed, stride NFT)
__global__ void conv_mem(const void* __restrict__ mk, const void* __restrict__ mv,
                         ushort* __restrict__ kf, ushort* __restrict__ vT,
                         const int* __restrict__ modep){
  int idx = blockIdx.x*256 + threadIdx.x;
  constexpr int total = BATCH*NH*NMEM*HD;
  if (idx >= total) return;
  int dd = idx & 63;
  int j  = (idx >> 6) % NMEM;
  int bh = idx / (NMEM*HD);
  ushort k_, v_;
  if (modep[0]){ k_ = ((const ushort*)mk)[idx]; v_ = ((const ushort*)mv)[idx]; }
  else { k_ = f2bf(((const float*)mk)[idx]); v_ = f2bf(((const float*)mv)[idx]); }
  kf[((size_t)bh*NFULL + j)*HD + dd] = k_;
  vT[((size_t)bh*HD + dd)*NFT + j]   = v_;
}

// ======================= GEMM (m97 structure, 128x128 tile) =======================
#define GEMM_PROLOGUE(M_, Nc_, K_) \
  __shared__ ushort As[128][40]; \
  __shared__ ushort Bs[128][40]; \
  const int tid  = threadIdx.x; \
  const int wave = tid >> 6, lane = tid & 63; \
  const int quad = lane >> 4, l16 = lane & 15; \
  const int row0 = blockIdx.x * 128, col0 = blockIdx.y * 128; \
  const int wr = (wave >> 1) * 64, wc = (wave & 1) * 64; \
  f32x4 acc[4][4] = {}; \
  for (int k0 = 0; k0 < (K_); k0 += 32){ \
    __syncthreads(); \
    for (int c = tid; c < 512; c += 256){ \
      int r = c >> 2, ck = c & 3; \
      uint4 v = {0,0,0,0}; \
      int gr = row0 + r; \
      if (gr < (M_)) v = *(const uint4*)(A + (size_t)gr * (K_) + k0 + ck*8); \
      *(uint4*)(&As[r][ck*8]) = v; \
    } \
    for (int c = tid; c < 512; c += 256){ \
      int r = c >> 2, ck = c & 3; \
      uint4 v = {0,0,0,0}; \
      int gc = col0 + r; \
      if (gc < (Nc_)) v = *(const uint4*)(Bw + (size_t)gc * (K_) + k0 + ck*8); \
      *(uint4*)(&Bs[r][ck*8]) = v; \
    } \
    __syncthreads(); \
    bf16x8 af[4], bfr[4]; \
    _Pragma("unroll") \
    for (int i = 0; i < 4; i++) af[i]  = *(const bf16x8*)(&As[wr + 16*i + l16][quad*8]); \
    _Pragma("unroll") \
    for (int j = 0; j < 4; j++) bfr[j] = *(const bf16x8*)(&Bs[wc + 16*j + l16][quad*8]); \
    _Pragma("unroll") \
    for (int i = 0; i < 4; i++) \
      _Pragma("unroll") \
      for (int j = 0; j < 4; j++) \
        acc[i][j] = __builtin_amdgcn_mfma_f32_16x16x32_bf16(af[i], bfr[j], acc[i][j], 0, 0, 0); \
  }
// C/D layout (verified m89/m91): col = lane&15, row = (lane>>4)*4 + reg

__global__ __launch_bounds__(256)
void gemm_idkv(const ushort* __restrict__ A, const ushort* __restrict__ Bw,
               const float* __restrict__ biasf, float* __restrict__ Cf)
{
  constexpr int M = BATCH*NM, Nc = IDC, K = CDIM;
  GEMM_PROLOGUE(M, Nc, K)
  #pragma unroll
  for (int i = 0; i < 4; i++)
    #pragma unroll
    for (int j = 0; j < 4; j++)
      #pragma unroll
      for (int r = 0; r < 4; r++){
        int row = row0 + wr + 16*i + quad*4 + r;
        int col = col0 + wc + 16*j + l16;
        if (row < M && col < Nc)
          Cf[(size_t)row*Nc + col] = acc[i][j][r] + biasf[col];
      }
}

// qkv GEMM + fused epilogue: q->qallb(bf16,scaled), k->kfull tail + kmod + out_km,
// v->vT tail (transposed) + out_vm.
__global__ __launch_bounds__(256)
void gemm_qkv(const ushort* __restrict__ A, const ushort* __restrict__ Bw,
              const float* __restrict__ idkvf, ushort* __restrict__ qallb,
              ushort* __restrict__ kfull, ushort* __restrict__ vT,
              ushort* __restrict__ kmod, void* __restrict__ out_base,
              const int* __restrict__ modep)
{
  constexpr int M = BATCH*SEQ, Nc = 3*CDIM, K = CDIM;
  GEMM_PROLOGUE(M, Nc, K)
  const int mode = modep[0];
  constexpr size_t OKM = (size_t)BATCH*SEQ*CDIM;
  constexpr size_t OVM = OKM + (size_t)BATCH*NH*NM*HD;
  #pragma unroll
  for (int i = 0; i < 4; i++)
    #pragma unroll
    for (int j = 0; j < 4; j++)
      #pragma unroll
      for (int r = 0; r < 4; r++){
        int row = row0 + wr + 16*i + quad*4 + r;
        int col = col0 + wc + 16*j + l16;
        if (row < M && col < Nc){
          float v = acc[i][j][r];
          int b = row / SEQ, n = row - b*SEQ;
          if (col < CDIM){
            int h = col >> 6, dd = col & 63;
            qallb[((size_t)(b*NH+h)*SEQ + n)*HD + dd] = f2bf(v * 0.125f);
          } else if (col < 2*CDIM){
            int c = col - CDIM; int h = c >> 6, dd = c & 63;
            size_t bh = (size_t)b*NH + h;
            kfull[(bh*NFULL + NMEM + n)*HD + dd] = f2bf(v);
            if (n < NM){
              float idk = idkvf[((size_t)b*NM + n)*IDC + h];
              float km = v * (1.f + tanhf(idk));
              size_t o = (bh*NM + n)*HD + dd;
              kmod[o] = f2bf(km);
              if (mode) ((ushort*)out_base)[OKM + o] = f2bf(km);
              else      ((float*) out_base)[OKM + o] = km;
            }
          } else {
            int c = col - 2*CDIM; int h = c >> 6, dd = c & 63;
            size_t bh = (size_t)b*NH + h;
            float vv = v;
            if (n < NM){
              vv = v + idkvf[((size_t)b*NM + n)*IDC + NH + c];
              size_t o = (bh*NM + n)*HD + dd;
              if (mode) ((ushort*)out_base)[OVM + o] = f2bf(vv);
              else      ((float*) out_base)[OVM + o] = vv;
            }
            vT[(bh*HD + dd)*NFT + NMEM + n] = f2bf(vv);
          }
        }
      }
}

__global__ __launch_bounds__(256)
void gemm_proj(const ushort* __restrict__ A, const ushort* __restrict__ Bw,
               const float* __restrict__ biasf, void* __restrict__ out_base,
               const int* __restrict__ modep)
{
  constexpr int M = BATCH*SEQ, Nc = CDIM, K = CDIM;
  GEMM_PROLOGUE(M, Nc, K)
  const int mode = modep[0];
  #pragma unroll
  for (int i = 0; i < 4; i++)
    #pragma unroll
    for (int j = 0; j < 4; j++)
      #pragma unroll
      for (int r = 0; r < 4; r++){
        int row = row0 + wr + 16*i + quad*4 + r;
        int col = col0 + wc + 16*j + l16;
        if (row < M && col < Nc){
          float v = acc[i][j][r] + biasf[col];
          size_t o = (size_t)row*Nc + col;
          if (mode) ((ushort*)out_base)[o] = f2bf(v);
          else      ((float*) out_base)[o] = v;
        }
      }
}

// ======================= MFMA top-k attention =======================
// 32 q-rows per WG. Scores via MFMA -> int16-quantized (x1024) global slab.
// Exact 2-pass radix select on 16-bit monotone keys (32 rows in parallel),
// tie-break = smallest index (lax.top_k stable order). AV via MFMA with
// P recomputed inline and V pre-transposed (vT). Persistent item loop so
// the slab count adapts to ws_size.
__global__ __launch_bounds__(256, 4)
void attn_topk2(const ushort* __restrict__ qallb, const ushort* __restrict__ Kbase,
                int Krows, const ushort* __restrict__ vT, int vjoff,
                ushort* __restrict__ xcat, ushort* __restrict__ slab_base,
                size_t slab_stride, int items, int qtiles, int qbase,
                int nqtot, int Kn, int KnP, int ksel)
{
  __shared__ uint  ubuf[8192];          // 32KB union: hist | jlist(32x96) | redO(32x64 f32)
  __shared__ float rowmaxp[32][4];
  __shared__ float ms[32], zs[32], zpart[32][8];
  __shared__ uint  t8s[32], needs[32], cnts[32];
  __shared__ ushort tks[32];
  __shared__ int   jcuts[32];

  const int tid  = threadIdx.x;
  const int wave = tid >> 6, lane = tid & 63;
  const int quad = lane >> 4, l16 = lane & 15;
  const int rr8  = tid >> 3, sub = tid & 7;     // scan assignment: 8 threads/row
  ushort* slab = slab_base + (size_t)blockIdx.x * slab_stride;
  float* redf = (float*)ubuf;

  for (int it = blockIdx.x; it < items; it += gridDim.x){
    const int bh = it / qtiles, qt = it % qtiles;
    const int b = bh / NH, h = bh % NH;
    const int q0 = qt * 32;
    const int nq = min(32, nqtot - q0);
    const ushort* Kb  = Kbase + (size_t)bh * Krows * HD;
    const ushort* qb  = qallb + (size_t)bh * SEQ * HD;
    const ushort* vTb = vT + (size_t)bh * HD * NFT + vjoff;

    // ---------- phase 1: scores via MFMA -> quantized slab + row max ----------
    bf16x8 afr[2][2];
    #pragma unroll
    for (int qf = 0; qf < 2; qf++)
      #pragma unroll
      for (int ds = 0; ds < 2; ds++){
        int qg = qbase + q0 + qf*16 + l16;
        if (qg > SEQ-1) qg = SEQ-1;
        afr[qf][ds] = *(const bf16x8*)(qb + (size_t)qg*HD + ds*32 + quad*8);
      }
    float pm[2][4];
    #pragma unroll
    for (int qf = 0; qf < 2; qf++)
      #pragma unroll
      for (int r = 0; r < 4; r++) pm[qf][r] = -3.0e38f;

    for (int j0 = wave*16; j0 < Kn; j0 += 64){
      int jj = j0 + l16;
      int jc = jj < Kn ? jj : Kn-1;
      const ushort* kr = Kb + (size_t)jc*HD;
      bf16x8 b0 = *(const bf16x8*)(kr + quad*8);
      bf16x8 b1 = *(const bf16x8*)(kr + 32 + quad*8);
      f32x4 c0 = {}, c1 = {};
      c0 = __builtin_amdgcn_mfma_f32_16x16x32_bf16(afr[0][0], b0, c0, 0,0,0);
      c0 = __builtin_amdgcn_mfma_f32_16x16x32_bf16(afr[0][1], b1, c0, 0,0,0);
      c1 = __builtin_amdgcn_mfma_f32_16x16x32_bf16(afr[1][0], b0, c1, 0,0,0);
      c1 = __builtin_amdgcn_mfma_f32_16x16x32_bf16(afr[1][1], b1, c1, 0,0,0);
      bool jv = jj < Kn;
      #pragma unroll
      for (int qf = 0; qf < 2; qf++){
        #pragma unroll
        for (int r = 0; r < 4; r++){
          float s = qf ? c1[r] : c0[r];
          int row = qf*16 + quad*4 + r;
          if (jv){
            pm[qf][r] = fmaxf(pm[qf][r], s);
            if (row < nq){
              int q16 = __float2int_rn(s * 1024.f);
              q16 = q16 > 32767 ? 32767 : (q16 < -32768 ? -32768 : q16);
              slab[row*KnP + jj] = (ushort)(short)q16;
            }
          }
        }
      }
    }
    // fill pad cols with key-min
    for (int t = tid; t < (KnP-Kn)*32; t += 256){
      int row = t / (KnP-Kn), j = Kn + t % (KnP-Kn);
      slab[row*KnP + j] = 0x8000;       // int16 -32768 -> monotone key 0
    }
    // row-max: shuffle-reduce across the 16 lanes sharing a quad
    #pragma unroll
    for (int qf = 0; qf < 2; qf++)
      #pragma unroll
      for (int r = 0; r < 4; r++){
        float v = pm[qf][r];
        #pragma unroll
        for (int mk = 1; mk < 16; mk <<= 1) v = fmaxf(v, __shfl_xor(v, mk));
        if (l16 == 0) rowmaxp[qf*16 + quad*4 + r][wave] = v;
      }
    __threadfence_block();
    __syncthreads();
    if (tid < 32)
      ms[tid] = fmaxf(fmaxf(rowmaxp[tid][0], rowmaxp[tid][1]),
                      fmaxf(rowmaxp[tid][2], rowmaxp[tid][3]));

    // ---------- phase 2: radix select (2 passes, 8-bit) ----------
    const ushort* srow = slab + (size_t)rr8 * KnP;
    for (int i = tid; i < 8192; i += 256) ubuf[i] = 0;
    __syncthreads();
    for (int j4 = sub*4; j4 < Kn; j4 += 32){
      ushort4 v = *(const ushort4*)(srow + j4);
      ushort va[4] = {v.x, v.y, v.z, v.w};
      #pragma unroll
      for (int e = 0; e < 4; e++){
        int j = j4 + e;
        if (j < Kn){
          uint key = (uint)va[e] ^ 0x8000u;
          atomicAdd(&ubuf[(rr8<<8) + (key>>8)], 1u);
        }
      }
    }
    __syncthreads();
    if (tid < 32){
      uint need = (uint)ksel, cum = 0; int bsel = 0;
      for (int bb = 255; bb >= 0; bb--){
        uint hc = ubuf[(tid<<8)+bb];
        if (cum + hc >= need){ bsel = bb; need -= cum; break; }
        cum += hc;
      }
      t8s[tid] = (uint)bsel; needs[tid] = need;
    }
    __syncthreads();
    for (int i = tid; i < 8192; i += 256) ubuf[i] = 0;
    __syncthreads();
    {
      uint t8r = t8s[rr8];
      for (int j4 = sub*4; j4 < Kn; j4 += 32){
        ushort4 v = *(const ushort4*)(srow + j4);
        ushort va[4] = {v.x, v.y, v.z, v.w};
        #pragma unroll
        for (int e = 0; e < 4; e++){
          int j = j4 + e;
          if (j < Kn){
            uint key = (uint)va[e] ^ 0x8000u;
            if ((key>>8) == t8r) atomicAdd(&ubuf[(rr8<<8) + (key&255u)], 1u);
          }
        }
      }
    }
    __syncthreads();
    if (tid < 32){
      uint need = needs[tid], cum = 0; int bsel = 0;
      for (int bb = 255; bb >= 0; bb--){
        uint hc = ubuf[(tid<<8)+bb];
        if (cum + hc >= need){ bsel = bb; need -= cum; break; }
        cum += hc;
      }
      tks[tid] = (ushort)((t8s[tid]<<8) | (uint)bsel);
      needs[tid] = need;
      cnts[tid] = 0;
    }
    __syncthreads();
    // ---------- phase 2b: collect boundary ties, jcut = need-th smallest j ----------
    {
      uint tkr = (uint)tks[rr8];
      for (int j4 = sub*4; j4 < Kn; j4 += 32){
        ushort4 v = *(const ushort4*)(srow + j4);
        ushort va[4] = {v.x, v.y, v.z, v.w};
        #pragma unroll
        for (int e = 0; e < 4; e++){
          int j = j4 + e;
          if (j < Kn){
            uint key = (uint)va[e] ^ 0x8000u;
            if (key == tkr){
              uint pos = atomicAdd(&cnts[rr8], 1u);
              if (pos < 96u) ubuf[rr8*96 + pos] = (uint)j;
            }
          }
        }
      }
    }
    __syncthreads();
    if (tid < 32){
      if (tid < nq){
        uint nd = needs[tid], n = min(cnts[tid], 96u);
        if (nd > n) nd = n;
        int jc = -1;
        for (uint t = 0; t < nd; t++){
          int mn = 0x7fffffff;
          for (uint i2 = 0; i2 < n; i2++){
            int jj = (int)ubuf[tid*96 + i2];
            if (jj > jc && jj < mn) mn = jj;
          }
          jc = mn;
        }
        jcuts[tid] = jc;
      } else {
        tks[tid] = 0xFFFF; jcuts[tid] = -1;
      }
    }
    __syncthreads();
    // ---------- phase 3: Z ----------
    {
      uint tkr = (uint)tks[rr8]; int jcr = jcuts[rr8]; float mr = ms[rr8];
      float zl = 0.f;
      for (int j4 = sub*4; j4 < Kn; j4 += 32){
        ushort4 v = *(const ushort4*)(srow + j4);
        ushort va[4] = {v.x, v.y, v.z, v.w};
        #pragma unroll
        for (int e = 0; e < 4; e++){
          int j = j4 + e;
          if (j < Kn){
            uint key = (uint)va[e] ^ 0x8000u;
            if (key > tkr || (key == tkr && j <= jcr))
              zl += __expf((float)(short)va[e] * (1.f/1024.f) - mr);
          }
        }
      }
      zpart[rr8][sub] = zl;
    }
    __syncthreads();
    if (tid < 32){
      float Z = 0.f;
      #pragma unroll
      for (int i2 = 0; i2 < 8; i2++) Z += zpart[tid][i2];
      zs[tid] = (tid < nq && Z > 0.f) ? 1.f/Z : 0.f;
    }
    // ---------- phase 4: AV via MFMA ----------
    for (int i = tid; i < 2048; i += 256) redf[i] = 0.f;
    __syncthreads();
    {
      f32x4 oacc[2][4] = {};
      uint  tkq[2]; int jcq[2]; float mq[2]; const ushort* srq[2];
      #pragma unroll
      for (int qf = 0; qf < 2; qf++){
        int row = qf*16 + l16;
        tkq[qf] = (uint)tks[row]; jcq[qf] = jcuts[row]; mq[qf] = ms[row];
        srq[qf] = slab + (size_t)row*KnP;
      }
      for (int j0 = wave*32; j0 < Kn; j0 += 128){
        int jb = j0 + quad*8;
        if (jb > KnP-8) jb = KnP-8;     // never shifts a tile containing valid j (mod-8)
        bf16x8 pa[2];
        #pragma unroll
        for (int qf = 0; qf < 2; qf++){
          ushort4 v0 = *(const ushort4*)(srq[qf] + jb);
          ushort4 v1 = *(const ushort4*)(srq[qf] + jb + 4);
          ushort va[8] = {v0.x,v0.y,v0.z,v0.w, v1.x,v1.y,v1.z,v1.w};
          union { bf16x8 v; ushort u[8]; } pk;
          #pragma unroll
          for (int e = 0; e < 8; e++){
            int j = jb + e;
            float ev = 0.f;
            if (j < Kn){
              uint key = (uint)va[e] ^ 0x8000u;
              if (key > tkq[qf] || (key == tkq[qf] && j <= jcq[qf]))
                ev = __expf((float)(short)va[e] * (1.f/1024.f) - mq[qf]);
            }
            pk.u[e] = f2bf(ev);
          }
          pa[qf] = pk.v;
        }
        #pragma unroll
        for (int df = 0; df < 4; df++){
          const ushort* vr = vTb + (size_t)(df*16 + l16)*NFT + jb;
          bf16x8 bv = *(const bf16x8*)vr;
          oacc[0][df] = __builtin_amdgcn_mfma_f32_16x16x32_bf16(pa[0], bv, oacc[0][df], 0,0,0);
          oacc[1][df] = __builtin_amdgcn_mfma_f32_16x16x32_bf16(pa[1], bv, oacc[1][df], 0,0,0);
        }
      }
      // cross-wave reduction (sequential, deterministic)
      for (int w = 0; w < 4; w++){
        if (wave == w){
          #pragma unroll
          for (int qf = 0; qf < 2; qf++)
            #pragma unroll
            for (int df = 0; df < 4; df++)
              #pragma unroll
              for (int r = 0; r < 4; r++)
                redf[(qf*16 + quad*4 + r)*64 + df*16 + l16] += oacc[qf][df][r];
        }
        __syncthreads();
      }
    }
    // ---------- store ----------
    {
      int row = tid >> 3, d0 = (tid & 7) * 8;
      if (row < nq){
        float zr = zs[row];
        uint4 ov; ushort* op = (ushort*)&ov;
        #pragma unroll
        for (int e = 0; e < 8; e++) op[e] = f2bf(redf[row*64 + d0 + e] * zr);
        int qg = qbase + q0 + row;
        *(uint4*)(xcat + ((size_t)b*SEQ + qg)*CDIM + h*HD + d0) = ov;
      }
    }
    // next item: phase-1-end barrier of the next iteration protects red/ubuf reuse
  }
}

// ======================= launch =======================
extern "C" void kernel_launch(void* const* d_in, const int* in_sizes, int n_in,
                              void* d_out, int out_size, void* d_ws, size_t ws_size,
                              hipStream_t stream)
{
  const void* x        = d_in[0];
  const void* id_total = d_in[1];
  const void* mem_k    = d_in[2];
  const void* mem_v    = d_in[3];
  const void* w_qkv    = d_in[4];
  const void* w_proj   = d_in[5];
  const void* b_proj   = d_in[6];
  const void* w_idkv   = d_in[7];
  const void* b_idkv   = d_in[8];

  char* p = (char*)d_ws;
  auto carve = [&](size_t bytes)->char*{
    char* q = p; p += (bytes + 255) & ~(size_t)255; return q;
  };
  int*    modep  = (int*)   carve(256);
  ushort* xb     = (ushort*)carve(2ull*BATCH*SEQ*CDIM);
  ushort* idb    = (ushort*)carve(2ull*BATCH*NM*CDIM);
  ushort* wqkvb  = (ushort*)carve(2ull*3*CDIM*CDIM);
  ushort* wprojb = (ushort*)carve(2ull*CDIM*CDIM);
  ushort* widkvb = (ushort*)carve(2ull*IDC*CDIM);
  float*  bprojf = (float*) carve(4ull*CDIM);
  float*  bidkvf = (float*) carve(4ull*IDC);
  float*  idkvf  = (float*) carve(4ull*BATCH*NM*IDC);
  ushort* qallb  = (ushort*)carve(2ull*BATCH*NH*SEQ*HD);
  ushort* kfull  = (ushort*)carve(2ull*BATCH*NH*NFULL*HD);
  ushort* vT     = (ushort*)carve(2ull*BATCH*NH*HD*NFT);
  ushort* kmod   = (ushort*)carve(2ull*BATCH*NH*NM*HD);
  ushort* xcat   = (ushort*)carve(2ull*BATCH*SEQ*CDIM);

  // adaptive slab pool (persistent attention WGs reuse slabs across items)
  constexpr int QT_S = (841 + 31) / 32;    // 27
  constexpr int QT_T = (NM + 31) / 32;     // 53
  const int items_s = BATCH*NH*QT_S;       // 648
  const int items_t = BATCH*NH*QT_T;       // 1272
  size_t used = (size_t)(p - (char*)d_ws);
  size_t remain = ws_size > used ? ws_size - used : 0;
  size_t stride_s = (size_t)32 * KNP_S;    // ushorts per slab
  size_t stride_t = (size_t)32 * KNP_T;
  int slabs_s = (int)(remain / (stride_s*2)); if (slabs_s > items_s) slabs_s = items_s;
  int slabs_t = (int)(remain / (stride_t*2)); if (slabs_t > items_t) slabs_t = items_t;
  if (slabs_s < 1) slabs_s = 1;
  if (slabs_t < 1) slabs_t = 1;
  size_t pool_bytes = stride_s*2*(size_t)slabs_s;
  size_t pool_t     = stride_t*2*(size_t)slabs_t;
  if (pool_t > pool_bytes) pool_bytes = pool_t;
  ushort* slab = (ushort*)carve(pool_bytes);

  dim3 blk(256,1,1);

  hipLaunchKernelGGL(detect_mode, dim3(1), blk, 0, stream, (const uint*)w_qkv, modep);

  auto conv = [&](const void* src, ushort* dst, int n){
    hipLaunchKernelGGL(conv_in, dim3((n+255)/256), blk, 0, stream, src, dst, n, modep);
  };
  conv(x,        xb,     BATCH*SEQ*CDIM);
  conv(id_total, idb,    BATCH*NM*CDIM);
  conv(w_qkv,    wqkvb,  3*CDIM*CDIM);
  conv(w_proj,   wprojb, CDIM*CDIM);
  conv(w_idkv,   widkvb, IDC*CDIM);
  hipLaunchKernelGGL(conv_bias, dim3((CDIM+255)/256), blk, 0, stream, b_proj, bprojf, CDIM, modep);
  hipLaunchKernelGGL(conv_bias, dim3((IDC+255)/256),  blk, 0, stream, b_idkv, bidkvf, IDC, modep);
  {
    constexpr int total = BATCH*NH*NMEM*HD;
    hipLaunchKernelGGL(conv_mem, dim3((total+255)/256), blk, 0, stream,
                       mem_k, mem_v, kfull, vT, modep);
  }
  {
    int M = BATCH*NM, Nc = IDC;
    dim3 grid((M+127)/128, (Nc+127)/128, 1);
    hipLaunchKernelGGL(gemm_idkv, grid, blk, 0, stream, idb, widkvb, bidkvf, idkvf);
  }
  {
    int M = BATCH*SEQ, Nc = 3*CDIM;
    dim3 grid((M+127)/128, (Nc+127)/128, 1);
    hipLaunchKernelGGL(gemm_qkv, grid, blk, 0, stream,
                       xb, wqkvb, idkvf, qallb, kfull, vT, kmod, d_out, modep);
  }
  { // template attention: q rows [0,NM), K=kmod, V=v_m_mod (vT cols [NMEM,..)), top 841/1682
    hipLaunchKernelGGL(attn_topk2, dim3(slabs_t), blk, 0, stream,
                       qallb, kmod, NM, vT, NMEM, xcat, slab, stride_t,
                       items_t, QT_T, 0, NM, NM, KNP_T, TOPM);
  }
  { // search attention: q rows [NM,SEQ), K=kfull, V=vT full, top 1654/6619
    hipLaunchKernelGGL(attn_topk2, dim3(slabs_s), blk, 0, stream,
                       qallb, kfull, NFULL, vT, 0, xcat, slab, stride_s,
                       items_s, QT_S, NM, SEQ-NM, NFULL, KNP_S, TOPS);
  }
  {
    int M = BATCH*SEQ, Nc = CDIM;
    dim3 grid((M+127)/128, (Nc+127)/128, 1);
    hipLaunchKernelGGL(gemm_proj, grid, blk, 0, stream, xcat, wprojb, bprojf, d_out, modep);
  }
}

// Round 4
// 1356.844 us; speedup vs baseline: 12.1128x; 1.9859x over previous
//
#include <hip/hip_runtime.h>
#include <cstddef>

typedef unsigned int uint;
typedef unsigned short ushort;

// ---- problem constants (from reference) ----
constexpr int BATCH = 2;
constexpr int SEQ   = 2523;
constexpr int CDIM  = 768;
constexpr int NH    = 12;
constexpr int HD    = 64;
constexpr int NM    = 1682;               // template rows
constexpr int NMEM  = 4096;
constexpr int NFULL = NMEM + SEQ;         // 6619
constexpr int NFT   = 6656;               // vT padded row stride
constexpr int TOPM  = 841;                // int(0.50*1682)
constexpr int TOPS  = 1654;               // int(0.25*6619)
constexpr int IDC   = CDIM + NH;          // 780

using bf16x8 = __attribute__((ext_vector_type(8))) short;
using f32x4  = __attribute__((ext_vector_type(4))) float;

__device__ __forceinline__ float bf2f(ushort u){ return __uint_as_float(((uint)u) << 16); }
__device__ __forceinline__ ushort f2bf(float f){
  uint x = __float_as_uint(f);
  x += 0x7fffu + ((x >> 16) & 1u);        // RNE
  return (ushort)(x >> 16);
}
// 16-bit monotone selection key from score (x1024 fixed-point)
__device__ __forceinline__ uint qkey(float s){
  int q16 = __float2int_rn(s * 1024.f);
  q16 = q16 > 32767 ? 32767 : (q16 < -32768 ? -32768 : q16);
  return ((uint)(ushort)(short)q16) ^ 0x8000u;
}

// ======================= dtype detector =======================
__global__ void detect_mode(const uint* __restrict__ w, int* __restrict__ mode){
  __shared__ int cnt;
  if (threadIdx.x == 0) cnt = 0;
  __syncthreads();
  uint v = w[threadIdx.x * 97];
  uint e = (v >> 7) & 0xFFu;
  if (e >= 100u && e <= 135u) atomicAdd(&cnt, 1);
  __syncthreads();
  if (threadIdx.x == 0) mode[0] = (cnt > 128) ? 1 : 0;   // 1 = bf16, 0 = fp32
}

// ======================= input conversion =======================
__global__ void conv_in(const void* __restrict__ src, ushort* __restrict__ dst,
                        int n, const int* __restrict__ modep){
  int i = blockIdx.x*256 + threadIdx.x;
  if (i >= n) return;
  if (modep[0]) dst[i] = ((const ushort*)src)[i];
  else          dst[i] = f2bf(((const float*)src)[i]);
}

__global__ void conv_bias(const void* __restrict__ src, float* __restrict__ dst,
                          int n, const int* __restrict__ modep){
  int i = blockIdx.x*256 + threadIdx.x;
  if (i >= n) return;
  dst[i] = modep[0] ? bf2f(((const ushort*)src)[i]) : ((const float*)src)[i];
}

// mem_k -> kfull head (row-major); mem_v -> vT head (transposed, stride NFT)
__global__ void conv_mem(const void* __restrict__ mk, const void* __restrict__ mv,
                         ushort* __restrict__ kf, ushort* __restrict__ vT,
                         const int* __restrict__ modep){
  int idx = blockIdx.x*256 + threadIdx.x;
  constexpr int total = BATCH*NH*NMEM*HD;
  if (idx >= total) return;
  int dd = idx & 63;
  int j  = (idx >> 6) % NMEM;
  int bh = idx / (NMEM*HD);
  ushort k_, v_;
  if (modep[0]){ k_ = ((const ushort*)mk)[idx]; v_ = ((const ushort*)mv)[idx]; }
  else { k_ = f2bf(((const float*)mk)[idx]); v_ = f2bf(((const float*)mv)[idx]); }
  kf[((size_t)bh*NFULL + j)*HD + dd] = k_;
  vT[((size_t)bh*HD + dd)*NFT + j]   = v_;
}

// ======================= GEMM (m97 structure, 128x128 tile) =======================
#define GEMM_PROLOGUE(M_, Nc_, K_) \
  __shared__ ushort As[128][40]; \
  __shared__ ushort Bs[128][40]; \
  const int tid  = threadIdx.x; \
  const int wave = tid >> 6, lane = tid & 63; \
  const int quad = lane >> 4, l16 = lane & 15; \
  const int row0 = blockIdx.x * 128, col0 = blockIdx.y * 128; \
  const int wr = (wave >> 1) * 64, wc = (wave & 1) * 64; \
  f32x4 acc[4][4] = {}; \
  for (int k0 = 0; k0 < (K_); k0 += 32){ \
    __syncthreads(); \
    for (int c = tid; c < 512; c += 256){ \
      int r = c >> 2, ck = c & 3; \
      uint4 v = {0,0,0,0}; \
      int gr = row0 + r; \
      if (gr < (M_)) v = *(const uint4*)(A + (size_t)gr * (K_) + k0 + ck*8); \
      *(uint4*)(&As[r][ck*8]) = v; \
    } \
    for (int c = tid; c < 512; c += 256){ \
      int r = c >> 2, ck = c & 3; \
      uint4 v = {0,0,0,0}; \
      int gc = col0 + r; \
      if (gc < (Nc_)) v = *(const uint4*)(Bw + (size_t)gc * (K_) + k0 + ck*8); \
      *(uint4*)(&Bs[r][ck*8]) = v; \
    } \
    __syncthreads(); \
    bf16x8 af[4], bfr[4]; \
    _Pragma("unroll") \
    for (int i = 0; i < 4; i++) af[i]  = *(const bf16x8*)(&As[wr + 16*i + l16][quad*8]); \
    _Pragma("unroll") \
    for (int j = 0; j < 4; j++) bfr[j] = *(const bf16x8*)(&Bs[wc + 16*j + l16][quad*8]); \
    _Pragma("unroll") \
    for (int i = 0; i < 4; i++) \
      _Pragma("unroll") \
      for (int j = 0; j < 4; j++) \
        acc[i][j] = __builtin_amdgcn_mfma_f32_16x16x32_bf16(af[i], bfr[j], acc[i][j], 0, 0, 0); \
  }
// C/D layout (verified m89/m91): col = lane&15, row = (lane>>4)*4 + reg

__global__ __launch_bounds__(256)
void gemm_idkv(const ushort* __restrict__ A, const ushort* __restrict__ Bw,
               const float* __restrict__ biasf, float* __restrict__ Cf)
{
  constexpr int M = BATCH*NM, Nc = IDC, K = CDIM;
  GEMM_PROLOGUE(M, Nc, K)
  #pragma unroll
  for (int i = 0; i < 4; i++)
    #pragma unroll
    for (int j = 0; j < 4; j++)
      #pragma unroll
      for (int r = 0; r < 4; r++){
        int row = row0 + wr + 16*i + quad*4 + r;
        int col = col0 + wc + 16*j + l16;
        if (row < M && col < Nc)
          Cf[(size_t)row*Nc + col] = acc[i][j][r] + biasf[col];
      }
}

// qkv GEMM + fused epilogue: q->qallb(bf16,scaled), k->kfull tail + kmod + out_km,
// v->vT tail (transposed) + out_vm.
__global__ __launch_bounds__(256)
void gemm_qkv(const ushort* __restrict__ A, const ushort* __restrict__ Bw,
              const float* __restrict__ idkvf, ushort* __restrict__ qallb,
              ushort* __restrict__ kfull, ushort* __restrict__ vT,
              ushort* __restrict__ kmod, void* __restrict__ out_base,
              const int* __restrict__ modep)
{
  constexpr int M = BATCH*SEQ, Nc = 3*CDIM, K = CDIM;
  GEMM_PROLOGUE(M, Nc, K)
  const int mode = modep[0];
  constexpr size_t OKM = (size_t)BATCH*SEQ*CDIM;
  constexpr size_t OVM = OKM + (size_t)BATCH*NH*NM*HD;
  #pragma unroll
  for (int i = 0; i < 4; i++)
    #pragma unroll
    for (int j = 0; j < 4; j++)
      #pragma unroll
      for (int r = 0; r < 4; r++){
        int row = row0 + wr + 16*i + quad*4 + r;
        int col = col0 + wc + 16*j + l16;
        if (row < M && col < Nc){
          float v = acc[i][j][r];
          int b = row / SEQ, n = row - b*SEQ;
          if (col < CDIM){
            int h = col >> 6, dd = col & 63;
            qallb[((size_t)(b*NH+h)*SEQ + n)*HD + dd] = f2bf(v * 0.125f);
          } else if (col < 2*CDIM){
            int c = col - CDIM; int h = c >> 6, dd = c & 63;
            size_t bh = (size_t)b*NH + h;
            kfull[(bh*NFULL + NMEM + n)*HD + dd] = f2bf(v);
            if (n < NM){
              float idk = idkvf[((size_t)b*NM + n)*IDC + h];
              float km = v * (1.f + tanhf(idk));
              size_t o = (bh*NM + n)*HD + dd;
              kmod[o] = f2bf(km);
              if (mode) ((ushort*)out_base)[OKM + o] = f2bf(km);
              else      ((float*) out_base)[OKM + o] = km;
            }
          } else {
            int c = col - 2*CDIM; int h = c >> 6, dd = c & 63;
            size_t bh = (size_t)b*NH + h;
            float vv = v;
            if (n < NM){
              vv = v + idkvf[((size_t)b*NM + n)*IDC + NH + c];
              size_t o = (bh*NM + n)*HD + dd;
              if (mode) ((ushort*)out_base)[OVM + o] = f2bf(vv);
              else      ((float*) out_base)[OVM + o] = vv;
            }
            vT[(bh*HD + dd)*NFT + NMEM + n] = f2bf(vv);
          }
        }
      }
}

__global__ __launch_bounds__(256)
void gemm_proj(const ushort* __restrict__ A, const ushort* __restrict__ Bw,
               const float* __restrict__ biasf, void* __restrict__ out_base,
               const int* __restrict__ modep)
{
  constexpr int M = BATCH*SEQ, Nc = CDIM, K = CDIM;
  GEMM_PROLOGUE(M, Nc, K)
  const int mode = modep[0];
  #pragma unroll
  for (int i = 0; i < 4; i++)
    #pragma unroll
    for (int j = 0; j < 4; j++)
      #pragma unroll
      for (int r = 0; r < 4; r++){
        int row = row0 + wr + 16*i + quad*4 + r;
        int col = col0 + wc + 16*j + l16;
        if (row < M && col < Nc){
          float v = acc[i][j][r] + biasf[col];
          size_t o = (size_t)row*Nc + col;
          if (mode) ((ushort*)out_base)[o] = f2bf(v);
          else      ((float*) out_base)[o] = v;
        }
      }
}

// ======================= slab-free MFMA top-k attention =======================
// 32 q-rows per WG. Scores are RECOMPUTED via MFMA per phase (deterministic dag
// -> bitwise-identical each pass), never stored globally.
//  P1: hi-byte histogram (LDS 32x257, stride-padded: row scans hit distinct banks)
//  P2: lo-byte histogram of boundary bucket + tie-candidate list (cap 64; on
//      overflow take all ties -- Z stays self-consistent since Z = sum of mask)
//  P3: mask+exp(s - tval) -> bf16 P-tile via wave-private LDS transpose -> AV
//      MFMA against vT; Z accumulated in-register alongside.
__device__ __forceinline__ void score_tile(
    const bf16x8 afr[2][2], const ushort* __restrict__ Kb, int Kn,
    int j0, int l16, int quad, f32x4 cg[2][2])
{
  #pragma unroll
  for (int g = 0; g < 2; g++){
    int jj = j0 + g*16 + l16;
    int jc = jj < Kn ? jj : Kn-1;
    const ushort* kr = Kb + (size_t)jc*HD;
    bf16x8 b0 = *(const bf16x8*)(kr + quad*8);
    bf16x8 b1 = *(const bf16x8*)(kr + 32 + quad*8);
    f32x4 c0 = {}, c1 = {};
    c0 = __builtin_amdgcn_mfma_f32_16x16x32_bf16(afr[0][0], b0, c0, 0,0,0);
    c0 = __builtin_amdgcn_mfma_f32_16x16x32_bf16(afr[0][1], b1, c0, 0,0,0);
    c1 = __builtin_amdgcn_mfma_f32_16x16x32_bf16(afr[1][0], b0, c1, 0,0,0);
    c1 = __builtin_amdgcn_mfma_f32_16x16x32_bf16(afr[1][1], b1, c1, 0,0,0);
    cg[0][g] = c0; cg[1][g] = c1;
  }
}

__global__ __launch_bounds__(256, 2)
void attn_topk3(const ushort* __restrict__ qallb, const ushort* __restrict__ Kbase,
                const ushort* __restrict__ vT, int vjoff, ushort* __restrict__ xcat,
                int qtiles, int qbase, int nqtot, int Kn, int ksel)
{
  __shared__ uint ubuf[10272];          // hist 32x257 | lst 32x64 | (late) redf 2048 f32
  __shared__ ushort Pt[4][32][36];      // per-wave P transpose tile [wave][jl][row]
  __shared__ float zpart[32][4];
  __shared__ uint hi8[32], needs[32], tks[32], cnts[32];
  __shared__ int jcuts[32];
  uint* lst = ubuf + 8224;
  float* redf = (float*)ubuf;

  const int tid = threadIdx.x;
  const int wave = tid >> 6, lane = tid & 63;
  const int quad = lane >> 4, l16 = lane & 15;
  const int it = blockIdx.x;
  const int bh = it / qtiles, qt = it % qtiles;
  const int b = bh / NH, h = bh % NH;
  const int q0 = qt * 32;
  const int nq = min(32, nqtot - q0);
  const ushort* Kb  = Kbase + (size_t)bh * Kn * HD;
  const ushort* qb  = qallb + (size_t)bh * SEQ * HD;
  const ushort* vTb = vT + (size_t)bh * HD * NFT + vjoff;

  bf16x8 afr[2][2];
  #pragma unroll
  for (int qf = 0; qf < 2; qf++)
    #pragma unroll
    for (int ds = 0; ds < 2; ds++){
      int qg = qbase + q0 + qf*16 + l16;
      if (qg > SEQ-1) qg = SEQ-1;
      afr[qf][ds] = *(const bf16x8*)(qb + (size_t)qg*HD + ds*32 + quad*8);
    }

  // ---------- pass 1: hi-byte histogram ----------
  for (int i = tid; i < 10272; i += 256) ubuf[i] = 0;
  __syncthreads();
  for (int j0 = wave*32; j0 < Kn; j0 += 128){
    f32x4 cg[2][2];
    score_tile(afr, Kb, Kn, j0, l16, quad, cg);
    #pragma unroll
    for (int qf = 0; qf < 2; qf++)
      #pragma unroll
      for (int g = 0; g < 2; g++){
        int jj = j0 + g*16 + l16;
        if (jj < Kn){
          #pragma unroll
          for (int r = 0; r < 4; r++){
            int row = qf*16 + quad*4 + r;
            uint key = qkey(cg[qf][g][r]);
            atomicAdd(&ubuf[row*257 + (key>>8)], 1u);
          }
        }
      }
  }
  __syncthreads();
  if (tid < 32){
    uint need = (uint)ksel, cum = 0; int bsel = 0;
    for (int bb = 255; bb >= 0; bb--){
      uint hc = ubuf[tid*257 + bb];
      if (cum + hc >= need){ bsel = bb; need -= cum; break; }
      cum += hc;
    }
    hi8[tid] = (uint)bsel; needs[tid] = need;
  }
  __syncthreads();
  for (int i = tid; i < 10272; i += 256) ubuf[i] = 0;
  if (tid < 32) cnts[tid] = 0;
  __syncthreads();

  // ---------- pass 2: lo-byte histogram of boundary bucket + tie list ----------
  for (int j0 = wave*32; j0 < Kn; j0 += 128){
    f32x4 cg[2][2];
    score_tile(afr, Kb, Kn, j0, l16, quad, cg);
    #pragma unroll
    for (int qf = 0; qf < 2; qf++)
      #pragma unroll
      for (int g = 0; g < 2; g++){
        int jj = j0 + g*16 + l16;
        if (jj < Kn){
          #pragma unroll
          for (int r = 0; r < 4; r++){
            int row = qf*16 + quad*4 + r;
            uint key = qkey(cg[qf][g][r]);
            if ((key>>8) == hi8[row]){
              atomicAdd(&ubuf[row*257 + (key&255u)], 1u);
              uint pos = atomicAdd(&cnts[row], 1u);
              if (pos < 64u) lst[row*64 + pos] = ((key&255u)<<16) | (uint)jj;
            }
          }
        }
      }
  }
  __syncthreads();
  if (tid < 32){
    uint need = needs[tid], cum = 0; int bsel = 0;
    for (int bb = 255; bb >= 0; bb--){
      uint hc = ubuf[tid*257 + bb];
      if (cum + hc >= need){ bsel = bb; need -= cum; break; }
      cum += hc;
    }
    tks[tid] = (hi8[tid]<<8) | (uint)bsel;
    uint n = cnts[tid];
    int jc;
    if (n > 64u) jc = Kn;               // overflow fallback: take all ties
    else {
      jc = -1;
      for (uint t = 0; t < need; t++){
        int mn = 0x7fffffff;
        for (uint i2 = 0; i2 < n; i2++){
          uint e = lst[tid*64 + i2];
          if ((e>>16) == (uint)bsel){
            int j = (int)(e & 0xFFFFu);
            if (j > jc && j < mn) mn = j;
          }
        }
        if (mn == 0x7fffffff) break;
        jc = mn;
      }
    }
    jcuts[tid] = jc;
  }
  __syncthreads();

  // ---------- pass 3: P + AV MFMA + Z ----------
  f32x4 oacc[2][4] = {};
  float zacc[2][4] = {};
  uint tkq[2][4]; int jcq[2][4]; float tvq[2][4];
  #pragma unroll
  for (int qf = 0; qf < 2; qf++)
    #pragma unroll
    for (int r = 0; r < 4; r++){
      int row = qf*16 + quad*4 + r;
      tkq[qf][r] = tks[row]; jcq[qf][r] = jcuts[row];
      tvq[qf][r] = (float)(short)(ushort)(tks[row] ^ 0x8000u) * (1.f/1024.f);
    }

  for (int j0 = wave*32; j0 < Kn; j0 += 128){
    f32x4 cg[2][2];
    score_tile(afr, Kb, Kn, j0, l16, quad, cg);
    // form P (bf16) into wave-private transpose tile
    #pragma unroll
    for (int qf = 0; qf < 2; qf++)
      #pragma unroll
      for (int g = 0; g < 2; g++){
        int jj = j0 + g*16 + l16;
        ushort4 pk;
        ushort* pku = (ushort*)&pk;
        #pragma unroll
        for (int r = 0; r < 4; r++){
          float e = 0.f;
          if (jj < Kn){
            float s = cg[qf][g][r];
            uint key = qkey(s);
            if (key > tkq[qf][r] || (key == tkq[qf][r] && jj <= jcq[qf][r])){
              e = __expf(s - tvq[qf][r]);
              zacc[qf][r] += e;
            }
          }
          pku[r] = f2bf(e);
        }
        *(ushort4*)(&Pt[wave][g*16 + l16][qf*16 + quad*4]) = pk;
      }
    // AV: A = P (rows 16 x jl 32), B = vT (jl 32 x dd 16)
    bf16x8 pa[2];
    #pragma unroll
    for (int qf = 0; qf < 2; qf++){
      union { bf16x8 v; ushort u[8]; } pu;
      #pragma unroll
      for (int e = 0; e < 8; e++) pu.u[e] = Pt[wave][quad*8 + e][qf*16 + l16];
      pa[qf] = pu.v;
    }
    #pragma unroll
    for (int df = 0; df < 4; df++){
      bf16x8 bv = *(const bf16x8*)(vTb + (size_t)(df*16 + l16)*NFT + j0 + quad*8);
      oacc[0][df] = __builtin_amdgcn_mfma_f32_16x16x32_bf16(pa[0], bv, oacc[0][df], 0,0,0);
      oacc[1][df] = __builtin_amdgcn_mfma_f32_16x16x32_bf16(pa[1], bv, oacc[1][df], 0,0,0);
    }
  }

  // Z: reduce across the 16 j-lanes, then across waves
  #pragma unroll
  for (int qf = 0; qf < 2; qf++)
    #pragma unroll
    for (int r = 0; r < 4; r++){
      float v = zacc[qf][r];
      #pragma unroll
      for (int mk = 1; mk < 16; mk <<= 1) v += __shfl_xor(v, mk);
      if (l16 == 0) zpart[qf*16 + quad*4 + r][wave] = v;
    }
  __syncthreads();

  // O: sequential cross-wave reduction into redf (reuses ubuf)
  for (int w = 0; w < 4; w++){
    if (wave == w){
      #pragma unroll
      for (int qf = 0; qf < 2; qf++)
        #pragma unroll
        for (int df = 0; df < 4; df++)
          #pragma unroll
          for (int r = 0; r < 4; r++){
            int idx = (qf*16 + quad*4 + r)*64 + df*16 + l16;
            if (w == 0) redf[idx]  = oacc[qf][df][r];
            else        redf[idx] += oacc[qf][df][r];
          }
    }
    __syncthreads();
  }

  // store
  {
    int row = tid >> 3, d0 = (tid & 7) * 8;
    if (row < nq){
      float Z = zpart[row][0] + zpart[row][1] + zpart[row][2] + zpart[row][3];
      float zinv = Z > 0.f ? 1.f/Z : 0.f;
      uint4 ov; ushort* op = (ushort*)&ov;
      #pragma unroll
      for (int e = 0; e < 8; e++) op[e] = f2bf(redf[row*64 + d0 + e] * zinv);
      int qg = qbase + q0 + row;
      *(uint4*)(xcat + ((size_t)b*SEQ + qg)*CDIM + h*HD + d0) = ov;
    }
  }
}

// ======================= launch =======================
extern "C" void kernel_launch(void* const* d_in, const int* in_sizes, int n_in,
                              void* d_out, int out_size, void* d_ws, size_t ws_size,
                              hipStream_t stream)
{
  const void* x        = d_in[0];
  const void* id_total = d_in[1];
  const void* mem_k    = d_in[2];
  const void* mem_v    = d_in[3];
  const void* w_qkv    = d_in[4];
  const void* w_proj   = d_in[5];
  const void* b_proj   = d_in[6];
  const void* w_idkv   = d_in[7];
  const void* b_idkv   = d_in[8];

  char* p = (char*)d_ws;
  auto carve = [&](size_t bytes)->char*{
    char* q = p; p += (bytes + 255) & ~(size_t)255; return q;
  };
  int*    modep  = (int*)   carve(256);
  ushort* xb     = (ushort*)carve(2ull*BATCH*SEQ*CDIM);
  ushort* idb    = (ushort*)carve(2ull*BATCH*NM*CDIM);
  ushort* wqkvb  = (ushort*)carve(2ull*3*CDIM*CDIM);
  ushort* wprojb = (ushort*)carve(2ull*CDIM*CDIM);
  ushort* widkvb = (ushort*)carve(2ull*IDC*CDIM);
  float*  bprojf = (float*) carve(4ull*CDIM);
  float*  bidkvf = (float*) carve(4ull*IDC);
  float*  idkvf  = (float*) carve(4ull*BATCH*NM*IDC);
  ushort* qallb  = (ushort*)carve(2ull*BATCH*NH*SEQ*HD);
  ushort* kfull  = (ushort*)carve(2ull*BATCH*NH*NFULL*HD);
  ushort* vT     = (ushort*)carve(2ull*BATCH*NH*HD*NFT);
  ushort* kmod   = (ushort*)carve(2ull*BATCH*NH*NM*HD);
  ushort* xcat   = (ushort*)carve(2ull*BATCH*SEQ*CDIM);

  dim3 blk(256,1,1);

  hipLaunchKernelGGL(detect_mode, dim3(1), blk, 0, stream, (const uint*)w_qkv, modep);

  auto conv = [&](const void* src, ushort* dst, int n){
    hipLaunchKernelGGL(conv_in, dim3((n+255)/256), blk, 0, stream, src, dst, n, modep);
  };
  conv(x,        xb,     BATCH*SEQ*CDIM);
  conv(id_total, idb,    BATCH*NM*CDIM);
  conv(w_qkv,    wqkvb,  3*CDIM*CDIM);
  conv(w_proj,   wprojb, CDIM*CDIM);
  conv(w_idkv,   widkvb, IDC*CDIM);
  hipLaunchKernelGGL(conv_bias, dim3((CDIM+255)/256), blk, 0, stream, b_proj, bprojf, CDIM, modep);
  hipLaunchKernelGGL(conv_bias, dim3((IDC+255)/256),  blk, 0, stream, b_idkv, bidkvf, IDC, modep);
  {
    constexpr int total = BATCH*NH*NMEM*HD;
    hipLaunchKernelGGL(conv_mem, dim3((total+255)/256), blk, 0, stream,
                       mem_k, mem_v, kfull, vT, modep);
  }
  {
    int M = BATCH*NM, Nc = IDC;
    dim3 grid((M+127)/128, (Nc+127)/128, 1);
    hipLaunchKernelGGL(gemm_idkv, grid, blk, 0, stream, idb, widkvb, bidkvf, idkvf);
  }
  {
    int M = BATCH*SEQ, Nc = 3*CDIM;
    dim3 grid((M+127)/128, (Nc+127)/128, 1);
    hipLaunchKernelGGL(gemm_qkv, grid, blk, 0, stream,
                       xb, wqkvb, idkvf, qallb, kfull, vT, kmod, d_out, modep);
  }
  { // template attention: q rows [0,NM), K=kmod, V cols [NMEM,NMEM+NM), top 841/1682
    constexpr int QT_T = (NM + 31) / 32;          // 53
    hipLaunchKernelGGL(attn_topk3, dim3(BATCH*NH*QT_T), blk, 0, stream,
                       qallb, kmod, vT, NMEM, xcat, QT_T, 0, NM, NM, TOPM);
  }
  { // search attention: q rows [NM,SEQ), K=kfull, V full, top 1654/6619
    constexpr int QT_S = (SEQ - NM + 31) / 32;    // 27
    hipLaunchKernelGGL(attn_topk3, dim3(BATCH*NH*QT_S), blk, 0, stream,
                       qallb, kfull, vT, 0, xcat, QT_S, NM, SEQ-NM, NFULL, TOPS);
  }
  {
    int M = BATCH*SEQ, Nc = CDIM;
    dim3 grid((M+127)/128, (Nc+127)/128, 1);
    hipLaunchKernelGGL(gemm_proj, grid, blk, 0, stream, xcat, wprojb, bprojf, d_out, modep);
  }
}